// Round 1
// baseline (582.494 us; speedup 1.0000x reference)
//
#include <hip/hip_runtime.h>
#include <cmath>

// Problem constants
#define D_MODEL 1024
#define KOSC    256
#define NSEQ    4096
#define BATCH   4
#define NROW    (BATCH * NSEQ)   // 16384 rows (b*n)
#define JTOT    1792             // 6K proj + K phase

typedef short      s16x8 __attribute__((ext_vector_type(8)));
typedef float      f32x4 __attribute__((ext_vector_type(4)));

// async global->LDS, 16B per lane; LDS dest = wave-uniform base + lane*16
#define GL2LDS(gsrc, ldst)                                                      \
  __builtin_amdgcn_global_load_lds(                                             \
      (const __attribute__((address_space(1))) unsigned int*)(gsrc),            \
      (__attribute__((address_space(3))) unsigned int*)(ldst), 16, 0, 0)

__device__ __forceinline__ float sigm(float x) {
    return 1.0f / (1.0f + expf(-x));
}
__device__ __forceinline__ float softplusf_(float x) {
    return fmaxf(x, 0.0f) + log1pf(expf(-fabsf(x)));
}

// round-to-nearest-even bf16 split: f = hi + lo, residual ~2^-18 * |f|
__device__ __forceinline__ void bf16_split(float f, unsigned short& hi,
                                           unsigned short& lo) {
    unsigned u = __float_as_uint(f);
    unsigned r = u + 0x7FFFu + ((u >> 16) & 1u);
    hi = (unsigned short)(r >> 16);
    float fh = __uint_as_float((unsigned)hi << 16);
    float fl = f - fh;
    unsigned ul = __float_as_uint(fl);
    unsigned rl = ul + 0x7FFFu + ((ul >> 16) & 1u);
    lo = (unsigned short)(rl >> 16);
}

// ---------------------------------------------------------------------------
// split_x: x fp32 (16384x1024) -> XH, XL bf16 (in d_out scratch)
// ---------------------------------------------------------------------------
__global__ __launch_bounds__(256) void split_x_kernel(
    const float* __restrict__ x, unsigned short* __restrict__ XH,
    unsigned short* __restrict__ XL)
{
    int i = blockIdx.x * 256 + threadIdx.x;    // x4 floats
    float4 v = ((const float4*)x)[i];
    ushort4 h, l;
    bf16_split(v.x, h.x, l.x);
    bf16_split(v.y, h.y, l.y);
    bf16_split(v.z, h.z, l.z);
    bf16_split(v.w, h.w, l.w);
    ((ushort4*)XH)[i] = h;
    ((ushort4*)XL)[i] = l;
}

// ---------------------------------------------------------------------------
// split_w: [Wproj;Wphase] fp32 (1792x1024) -> WH, WL bf16
// ---------------------------------------------------------------------------
__global__ __launch_bounds__(256) void split_w_kernel(
    const float* __restrict__ Wproj, const float* __restrict__ Wphase,
    unsigned short* __restrict__ WH, unsigned short* __restrict__ WL)
{
    int i = blockIdx.x * 256 + threadIdx.x;    // x4 floats
    int elem = i << 2;
    int row = elem >> 10;
    int col = elem & 1023;
    const float* src = (row < 1536) ? (Wproj + (size_t)row * 1024 + col)
                                    : (Wphase + (size_t)(row - 1536) * 1024 + col);
    float4 v = *(const float4*)src;
    ushort4 h, l;
    bf16_split(v.x, h.x, l.x);
    bf16_split(v.y, h.y, l.y);
    bf16_split(v.z, h.z, l.z);
    bf16_split(v.w, h.w, l.w);
    ((ushort4*)WH)[i] = h;
    ((ushort4*)WL)[i] = l;
}

// ---------------------------------------------------------------------------
// pack_wres: W_res fp32 (1024 x 1022) -> WPH bf16 (1024 x 1024), padded 0
// ---------------------------------------------------------------------------
__global__ __launch_bounds__(256) void pack_wres_kernel(
    const float* __restrict__ Wres, unsigned short* __restrict__ WPH)
{
    int idx = blockIdx.x * 256 + threadIdx.x;   // 0 .. 1024*1024-1
    int d = idx >> 10;
    int j = idx & 1023;
    float v = (j < 1022) ? Wres[(size_t)d * 1022 + j] : 0.0f;
    unsigned u = __float_as_uint(v);
    unsigned r = u + 0x7FFFu + ((u >> 16) & 1u);
    WPH[idx] = (unsigned short)(r >> 16);
}

// ---------------------------------------------------------------------------
// 256x256-tile, 8-wave (2Mx4N), double-buffered, phase-interleaved GEMM core.
//
//   NKS    : K-steps (of 32) per K-tile; BK = 32*NKS.
//   HAS_AL : A has a lo term (3-term split path)
//   HAS_BL : B has a lo term
//
// LDS per operand array: [2 dbuf][256 rows][BK] bf16, granule (16B) index
// G = ksub*256 + row  (ksub-major => ds_read_b128 across fr is contiguous,
// conflict-free; matches gload_lds linear dest = wave-uniform base+lane*16).
//
// Schedule per K-tile kc (4 phases, quadrant qi,qj of the 128x64 wave tile):
//   boundary: asm vmcnt(0)  (loads for kc were issued in phases 0-1 of kc-1,
//             ~3 phases ago => wait is short)  + raw s_barrier (no compiler
//             vmcnt-drain as with __syncthreads)
//   phase p : ds_read quadrant frags; issue stage for kc+1 (p<2);
//             s_barrier; setprio(1); MFMA cluster; setprio(0); s_barrier
// Correctness: buf[nxt] (stage target) was last ds_read in kc-1; all those
// reads complete before each wave's kc-boundary barrier.
// ---------------------------------------------------------------------------
template<int NKS, int HAS_AL, int HAS_BL>
__device__ __forceinline__ void gemm256_core(
    const unsigned short* __restrict__ gAH, const unsigned short* __restrict__ gAL,
    const unsigned short* __restrict__ gBH, const unsigned short* __restrict__ gBL,
    unsigned short* sAH, unsigned short* sAL,
    unsigned short* sBH, unsigned short* sBL,
    int m0, int n0, f32x4 (&acc)[8][4])
{
    const int tid  = threadIdx.x;
    const int lane = tid & 63;
    const int w    = tid >> 6;      // wave 0..7
    const int wm   = w >> 2;        // 0..1  (M half)
    const int wn   = w & 3;         // 0..3  (N quarter)
    const int fr   = lane & 15;
    const int fq   = lane >> 4;     // 0..3
    const int BK   = 32 * NKS;
    const int BUFS = 256 * BK;      // shorts per buffer per array
    const int NKT  = 1024 / BK;     // K-tiles

    // one staging pass t: per array, 512 lanes x 16B = 8 KB (granules t*512..)
    auto stage = [&](int buf, int kc, int t) {
        const int G   = t * 512 + tid;       // granule index 0 .. 4*BK*8-1
        const int row = G & 255;
        const int q   = G >> 8;              // ksub 0..4*NKS-1
        const size_t ka   = (size_t)kc * BK + q * 8;
        const size_t offA = (size_t)(m0 + row) * 1024 + ka;
        const size_t offB = (size_t)(n0 + row) * 1024 + ka;
        const int ldso = buf * BUFS + (t * 512 + w * 64) * 8;  // wave-uniform
        GL2LDS(gAH + offA, &sAH[ldso]);
        if (HAS_AL) GL2LDS(gAL + offA, &sAL[ldso]);
        GL2LDS(gBH + offB, &sBH[ldso]);
        if (HAS_BL) GL2LDS(gBL + offB, &sBL[ldso]);
    };

    // prologue: stage K-tile 0 into buffer 0
    #pragma unroll
    for (int t = 0; t < 2 * NKS; t++) stage(0, 0, t);

    for (int kc = 0; kc < NKT; kc++) {
        const int cur   = kc & 1;
        const int cbase = cur * BUFS;
        // boundary: my loads for buf[cur] done; barrier => everyone's done.
        asm volatile("s_waitcnt vmcnt(0)" ::: "memory");
        __builtin_amdgcn_s_barrier();

        #pragma unroll
        for (int p = 0; p < 4; p++) {
            const int qi = p & 1;       // i-half  (i = qi*4 + ii)
            const int qj = p >> 1;      // j-half  (j = qj*2 + jj)

            s16x8 fah[4][NKS], fal[4][NKS], fbh[2][NKS], fbl[2][NKS];
            #pragma unroll
            for (int ii = 0; ii < 4; ii++) {
                const int i = qi * 4 + ii;
                #pragma unroll
                for (int s = 0; s < NKS; s++) {
                    const int off = cbase +
                        (((s * 4 + fq) * 256 + wm * 128 + i * 16 + fr) * 8);
                    fah[ii][s] = *(const s16x8*)&sAH[off];
                    if (HAS_AL) fal[ii][s] = *(const s16x8*)&sAL[off];
                }
            }
            #pragma unroll
            for (int jj = 0; jj < 2; jj++) {
                const int j = qj * 2 + jj;
                #pragma unroll
                for (int s = 0; s < NKS; s++) {
                    const int off = cbase +
                        (((s * 4 + fq) * 256 + wn * 64 + j * 16 + fr) * 8);
                    fbh[jj][s] = *(const s16x8*)&sBH[off];
                    if (HAS_BL) fbl[jj][s] = *(const s16x8*)&sBL[off];
                }
            }

            // issue next K-tile's loads early (phases 0-1)
            if (p < 2 && kc + 1 < NKT) {
                #pragma unroll
                for (int t = 0; t < NKS; t++)
                    stage(cur ^ 1, kc + 1, p * NKS + t);
            }

            __builtin_amdgcn_s_barrier();
            __builtin_amdgcn_s_setprio(1);
            #pragma unroll
            for (int ii = 0; ii < 4; ii++) {
                #pragma unroll
                for (int jj = 0; jj < 2; jj++) {
                    const int i = qi * 4 + ii;
                    const int j = qj * 2 + jj;
                    #pragma unroll
                    for (int s = 0; s < NKS; s++) {
                        acc[i][j] = __builtin_amdgcn_mfma_f32_16x16x32_bf16(
                            fah[ii][s], fbh[jj][s], acc[i][j], 0, 0, 0);
                        if (HAS_BL)
                            acc[i][j] = __builtin_amdgcn_mfma_f32_16x16x32_bf16(
                                fah[ii][s], fbl[jj][s], acc[i][j], 0, 0, 0);
                        if (HAS_AL)
                            acc[i][j] = __builtin_amdgcn_mfma_f32_16x16x32_bf16(
                                fal[ii][s], fbh[jj][s], acc[i][j], 0, 0, 0);
                    }
                }
            }
            __builtin_amdgcn_s_setprio(0);
            if (p < 3) __builtin_amdgcn_s_barrier();
            // (p==3 trailing barrier is subsumed by the next boundary barrier)
        }
    }
}

// ---------------------------------------------------------------------------
// GEMM1 unified: PT[j, r] = [W;Wphase] @ x^T (+bias).
//   yt=1,2 (omega, phi rows 256..767): 3-term split bf16 (feeds the angle).
//   yt=0,3..6: single bf16 (sigmoid-bounded outputs; bf16 ample).
// 256x256 tiles, merged so full+lite co-schedule across all 256 CUs.
// ---------------------------------------------------------------------------
__global__ __launch_bounds__(512, 2) void gemm1_kernel(
    const unsigned short* __restrict__ WH, const unsigned short* __restrict__ WL,
    const unsigned short* __restrict__ XH, const unsigned short* __restrict__ XL,
    const float* __restrict__ bproj, const float* __restrict__ bphase,
    float* __restrict__ PT)
{
    __shared__ __attribute__((aligned(16))) unsigned short smem[65536]; // 128 KB
    const int yt = blockIdx.y;          // 0..6 -> rows yt*256..
    const int m0 = yt * 256;
    const int n0 = blockIdx.x * 256;

    f32x4 acc[8][4];
    #pragma unroll
    for (int i = 0; i < 8; i++)
        #pragma unroll
        for (int j = 0; j < 4; j++) acc[i][j] = (f32x4){0.f, 0.f, 0.f, 0.f};

    if (yt == 1 || yt == 2) {
        // full: AH/AL/BH/BL @ 32 KB each (BK=32 dbuf)
        gemm256_core<1, 1, 1>(WH, WL, XH, XL,
                              smem, smem + 16384, smem + 32768, smem + 49152,
                              m0, n0, acc);
    } else {
        // lite: AH/BH @ 64 KB each (BK=64 dbuf)
        gemm256_core<2, 0, 0>(WH, nullptr, XH, nullptr,
                              smem, nullptr, smem + 32768, nullptr,
                              m0, n0, acc);
    }

    const int lane = threadIdx.x & 63;
    const int w    = threadIdx.x >> 6;
    const int wm   = w >> 2, wn = w & 3;
    const int fr   = lane & 15, fq = lane >> 4;
    #pragma unroll
    for (int i = 0; i < 8; i++) {
        const int mb = m0 + wm * 128 + i * 16 + fq * 4;
        #pragma unroll
        for (int j = 0; j < 4; j++) {
            const int n = n0 + wn * 64 + j * 16 + fr;
            #pragma unroll
            for (int rg = 0; rg < 4; rg++) {
                const int m = mb + rg;
                const float bias = (m < 1536) ? bproj[m] : bphase[m - 1536];
                PT[(size_t)m * NROW + n] = acc[i][j][rg] + bias;
            }
        }
    }
}

// ---------------------------------------------------------------------------
// Scan kernel: one block per (b, k) channel.
// ---------------------------------------------------------------------------
__global__ __launch_bounds__(256) void scan_kernel(float* PT,
                                                   const float* lambda_ptr)
{
    const int bx = blockIdx.x;         // 0..1023
    const int k = bx & 255;
    const int b = bx >> 8;
    const int t = threadIdx.x;         // 0..255
    const size_t colb = (size_t)b * NSEQ;
    const size_t R = NROW;

    float* rowA  = PT + (size_t)(k)        * R + colb;  // a_raw -> rho_re
    float* rowW  = PT + (size_t)(256 + k)  * R + colb;  // w_raw -> rho_im
    float* rowP  = PT + (size_t)(512 + k)  * R + colb;  // p_raw -> g
    float* rowAl = PT + (size_t)(768 + k)  * R + colb;  // al_raw
    float* rowG  = PT + (size_t)(1024 + k) * R + colb;  // g_raw
    float* rowBe = PT + (size_t)(1280 + k) * R + colb;  // be_raw
    float* rowPq = PT + (size_t)(1536 + k) * R + colb;  // phase query

    __shared__ float s_al[NSEQ + 256];
    __shared__ float s_rr[NSEQ + 256];
    __shared__ float s_ri[NSEQ + 256];
    __shared__ float s_sa[256], s_sbr[256], s_sbi[256];

    const float lam = *lambda_ptr;

    for (int i = 0; i < 16; i++) {
        int n = i * 256 + t;
        float araw = rowA[n];
        float wraw = rowW[n];
        float praw = rowP[n];
        float alraw = rowAl[n];
        float A     = 3.0f * sigm(araw);
        float alpha = sigm(alraw);
        float omega = softplusf_(wraw);
        float ang   = fmaf(omega, log1pf((float)n), praw);
        float sn, cs;
        sincosf(ang, &sn, &cs);
        float amp = (1.0f - alpha) * A;
        int pidx = n + (n >> 4);
        s_al[pidx] = alpha;
        s_rr[pidx] = amp * cs;
        s_ri[pidx] = amp * sn;
    }
    __syncthreads();

    {
        float ap = 1.0f, br = 0.0f, bi = 0.0f;
        int base = t * 17;
        #pragma unroll
        for (int i = 0; i < 16; i++) {
            float a = s_al[base + i];
            br = fmaf(a, br, s_rr[base + i]);
            bi = fmaf(a, bi, s_ri[base + i]);
            ap *= a;
        }
        s_sa[t] = ap; s_sbr[t] = br; s_sbi[t] = bi;
    }
    __syncthreads();

    for (int off = 1; off < 256; off <<= 1) {
        float a2 = s_sa[t], b2r = s_sbr[t], b2i = s_sbi[t];
        float a1 = 1.0f, b1r = 0.0f, b1i = 0.0f;
        if (t >= off) { a1 = s_sa[t - off]; b1r = s_sbr[t - off]; b1i = s_sbi[t - off]; }
        __syncthreads();
        s_sa[t]  = a1 * a2;
        s_sbr[t] = fmaf(a2, b1r, b2r);
        s_sbi[t] = fmaf(a2, b1i, b2i);
        __syncthreads();
    }

    {
        float cr = 0.0f, ci = 0.0f;
        if (t > 0) { cr = s_sbr[t - 1]; ci = s_sbi[t - 1]; }
        int base = t * 17;
        #pragma unroll
        for (int i = 0; i < 16; i++) {
            float a = s_al[base + i];
            cr = fmaf(a, cr, s_rr[base + i]);
            ci = fmaf(a, ci, s_ri[base + i]);
            s_rr[base + i] = cr;
            s_ri[base + i] = ci;
        }
    }
    __syncthreads();

    for (int i = 0; i < 16; i++) {
        int n = i * 256 + t;
        float wraw = rowW[n];
        float praw = rowP[n];
        float beraw = rowBe[n];
        float graw = rowG[n];
        float pq = rowPq[n];

        float omega = softplusf_(wraw);
        float ang = fmaf(omega, log1pf((float)n), praw);
        float sn, cs;
        sincosf(ang, &sn, &cs);

        int pidx = n + (n >> 4);
        float rr = s_rr[pidx], ri = s_ri[pidx];
        float beta = sigm(beraw);
        float g = sigm(graw);

        float readout = rr * cs + ri * sn;
        rr -= beta * readout * cs;
        ri -= beta * readout * sn;

        float modulus = sqrtf(rr * rr + ri * ri + 1e-8f);
        float scale = fmaxf(modulus, 1.0f);
        rr /= scale; ri /= scale;

        float rho_re = rr * cs + ri * sn;
        float rho_im = -rr * sn + ri * cs;

        float rho_norm = sqrtf(rho_re * rho_re + rho_im * rho_im + 1e-8f);
        float sq, cq;
        sincosf(pq, &sq, &cq);
        float pa = (rho_re * cq + rho_im * sq) / rho_norm;
        float gate = sigm(lam * pa);
        rho_re *= gate;
        rho_im *= gate;

        rowA[n] = rho_re;
        rowW[n] = rho_im;
        rowP[n] = g;
    }
}

// ---------------------------------------------------------------------------
// pack_rho: fused cross-products + transpose + bf16 split.
// ---------------------------------------------------------------------------
__global__ __launch_bounds__(256) void pack_rho_kernel(
    const float* __restrict__ PT, unsigned short* __restrict__ RTH,
    unsigned short* __restrict__ RTL)
{
    __shared__ float s_re[256 * 33];
    __shared__ float s_im[256 * 33];
    __shared__ float s_g [256 * 33];

    const int tid = threadIdx.x;
    const int r0 = blockIdx.x * 32;

    {
        int lr = tid & 31;
        int k0 = tid >> 5;       // 0..7
        for (int it = 0; it < 32; it++) {
            int k = it * 8 + k0;
            size_t go = (size_t)k * NROW + r0 + lr;
            s_re[k * 33 + lr] = PT[go];
            s_im[k * 33 + lr] = PT[(size_t)256 * NROW + go];
            s_g [k * 33 + lr] = PT[(size_t)512 * NROW + go];
        }
    }
    __syncthreads();

    const int r = tid >> 3;      // 0..31
    const int c = tid & 7;       // 0..7
    for (int i = 0; i < 16; i++) {
        int jb = (c + 8 * i) * 8;       // 0..1016, step 8
        unsigned short h[8], l[8];
        #pragma unroll
        for (int e = 0; e < 8; e++) {
            int j = jb + e;
            float v;
            if (j < 256) {
                v = s_g[j * 33 + r] * s_re[j * 33 + r];
            } else if (j < 512) {
                int k = j - 256;
                v = s_g[k * 33 + r] * s_im[k * 33 + r];
            } else if (j < 767) {
                int k = j - 512;
                float gc = 0.5f * (s_g[k * 33 + r] + s_g[(k + 1) * 33 + r]);
                v = gc * (s_re[k * 33 + r] * s_re[(k + 1) * 33 + r]
                        - s_im[k * 33 + r] * s_im[(k + 1) * 33 + r]);
            } else if (j < 1022) {
                int k = j - 767;
                float gc = 0.5f * (s_g[k * 33 + r] + s_g[(k + 1) * 33 + r]);
                v = gc * (s_re[k * 33 + r] * s_im[(k + 1) * 33 + r]
                        + s_im[k * 33 + r] * s_re[(k + 1) * 33 + r]);
            } else {
                v = 0.0f;
            }
            bf16_split(v, h[e], l[e]);
        }
        size_t off = (size_t)(r0 + r) * 1024 + jb;
        s16x8 hv, lv;
        #pragma unroll
        for (int e = 0; e < 8; e++) { hv[e] = (short)h[e]; lv[e] = (short)l[e]; }
        *(s16x8*)&RTH[off] = hv;
        *(s16x8*)&RTL[off] = lv;
    }
}

// ---------------------------------------------------------------------------
// GEMM2 (2-term: W_res bf16, rho hi+lo): out[r,d] = rs * sum_j RT[r,j]*WP[d,j]
// 256x256 tiles -> grid 64x4 = 256 blocks = 1/CU, zero tail.
// ---------------------------------------------------------------------------
__global__ __launch_bounds__(512, 2) void gemm2_kernel(
    const unsigned short* __restrict__ WPH,
    const unsigned short* __restrict__ RTH, const unsigned short* __restrict__ RTL,
    const float* __restrict__ rs_ptr, float* __restrict__ out)
{
    __shared__ __attribute__((aligned(16))) unsigned short smem[49152]; // 96 KB
    const int m0 = blockIdx.y * 256;    // d tile
    const int n0 = blockIdx.x * 256;    // r tile
    const float rs = *rs_ptr;

    f32x4 acc[8][4];
    #pragma unroll
    for (int i = 0; i < 8; i++)
        #pragma unroll
        for (int j = 0; j < 4; j++) acc[i][j] = (f32x4){0.f, 0.f, 0.f, 0.f};

    gemm256_core<1, 0, 1>(WPH, nullptr, RTH, RTL,
                          smem, nullptr, smem + 16384, smem + 32768,
                          m0, n0, acc);

    const int lane = threadIdx.x & 63;
    const int w    = threadIdx.x >> 6;
    const int wm   = w >> 2, wn = w & 3;
    const int fr   = lane & 15, fq = lane >> 4;
    #pragma unroll
    for (int i = 0; i < 8; i++) {
        const int d = m0 + wm * 128 + i * 16 + fq * 4;
        #pragma unroll
        for (int j = 0; j < 4; j++) {
            const int n = n0 + wn * 64 + j * 16 + fr;
            float4 v = { rs * acc[i][j][0], rs * acc[i][j][1],
                         rs * acc[i][j][2], rs * acc[i][j][3] };
            *(float4*)&out[(size_t)n * 1024 + d] = v;
        }
    }
}

// ---------------------------------------------------------------------------
extern "C" void kernel_launch(void* const* d_in, const int* in_sizes, int n_in,
                              void* d_out, int out_size, void* d_ws, size_t ws_size,
                              hipStream_t stream)
{
    const float* x      = (const float*)d_in[0];
    const float* Wproj  = (const float*)d_in[1];
    const float* bproj  = (const float*)d_in[2];
    const float* Wres   = (const float*)d_in[3];
    const float* Wphase = (const float*)d_in[4];
    const float* bphase = (const float*)d_in[5];
    const float* lam    = (const float*)d_in[6];
    const float* rs     = (const float*)d_in[7];
    float* out = (float*)d_out;

    // workspace layout (~124.8 MB):
    //   PT fp32 [1792][16384]           (117.4 MB)
    //   WH, WL bf16 [1792][1024]        (7.3 MB, after PT)
    // aliased into dead PT rows:
    //   RTH bf16 [16384][1024] = PT rows  768..1279
    //   RTL bf16 [16384][1024] = PT rows 1280..1791
    //   WPH bf16 [1024][1024]  = PT rows 0..31 (after pack_rho)
    // d_out doubles as XH/XL bf16 scratch until gemm2 overwrites it.
    float* PT = (float*)d_ws;
    unsigned short* WH  = (unsigned short*)((char*)d_ws + (size_t)JTOT * NROW * 4);
    unsigned short* WL  = WH + (size_t)JTOT * 1024;
    unsigned short* RTH = (unsigned short*)(PT + (size_t)768 * NROW);
    unsigned short* RTL = RTH + (size_t)NROW * 1024;
    unsigned short* WPH = (unsigned short*)PT;
    unsigned short* XH  = (unsigned short*)d_out;
    unsigned short* XL  = XH + (size_t)NROW * 1024;

    hipLaunchKernelGGL(split_x_kernel, dim3(NROW * D_MODEL / 1024), dim3(256), 0, stream,
                       x, XH, XL);
    hipLaunchKernelGGL(split_w_kernel, dim3(JTOT * D_MODEL / 1024), dim3(256), 0, stream,
                       Wproj, Wphase, WH, WL);
    hipLaunchKernelGGL(gemm1_kernel, dim3(NROW / 256, 7), dim3(512), 0, stream,
                       WH, WL, XH, XL, bproj, bphase, PT);
    hipLaunchKernelGGL(scan_kernel, dim3(BATCH * KOSC), dim3(256), 0, stream,
                       PT, lam);
    hipLaunchKernelGGL(pack_rho_kernel, dim3(NROW / 32), dim3(256), 0, stream,
                       PT, RTH, RTL);
    hipLaunchKernelGGL(pack_wres_kernel, dim3(1024 * 1024 / 256), dim3(256), 0, stream,
                       Wres, WPH);
    hipLaunchKernelGGL(gemm2_kernel, dim3(NROW / 256, 1024 / 256), dim3(512), 0, stream,
                       WPH, RTH, RTL, rs, out);
}

// Round 2
// 532.778 us; speedup vs baseline: 1.0933x; 1.0933x over previous
//
#include <hip/hip_runtime.h>
#include <cmath>

// Problem constants
#define D_MODEL 1024
#define KOSC    256
#define NSEQ    4096
#define BATCH   4
#define NROW    (BATCH * NSEQ)   // 16384 rows (b*n)
#define JTOT    1792             // 6K proj + K phase

typedef short      s16x8 __attribute__((ext_vector_type(8)));
typedef float      f32x4 __attribute__((ext_vector_type(4)));

// async global->LDS, 16B per lane; LDS dest = wave-uniform base + lane*16
#define GL2LDS(gsrc, ldst)                                                      \
  __builtin_amdgcn_global_load_lds(                                             \
      (const __attribute__((address_space(1))) unsigned int*)(gsrc),            \
      (__attribute__((address_space(3))) unsigned int*)(ldst), 16, 0, 0)

__device__ __forceinline__ float sigm(float x) {
    return 1.0f / (1.0f + expf(-x));
}
__device__ __forceinline__ float softplusf_(float x) {
    return fmaxf(x, 0.0f) + log1pf(expf(-fabsf(x)));
}

// round-to-nearest-even bf16 split: f = hi + lo, residual ~2^-18 * |f|
__device__ __forceinline__ void bf16_split(float f, unsigned short& hi,
                                           unsigned short& lo) {
    unsigned u = __float_as_uint(f);
    unsigned r = u + 0x7FFFu + ((u >> 16) & 1u);
    hi = (unsigned short)(r >> 16);
    float fh = __uint_as_float((unsigned)hi << 16);
    float fl = f - fh;
    unsigned ul = __float_as_uint(fl);
    unsigned rl = ul + 0x7FFFu + ((ul >> 16) & 1u);
    lo = (unsigned short)(rl >> 16);
}

// ---------------------------------------------------------------------------
// split_x: x fp32 (16384x1024) -> XH, XL bf16 (in d_out scratch)
// ---------------------------------------------------------------------------
__global__ __launch_bounds__(256) void split_x_kernel(
    const float* __restrict__ x, unsigned short* __restrict__ XH,
    unsigned short* __restrict__ XL)
{
    int i = blockIdx.x * 256 + threadIdx.x;    // x4 floats
    float4 v = ((const float4*)x)[i];
    ushort4 h, l;
    bf16_split(v.x, h.x, l.x);
    bf16_split(v.y, h.y, l.y);
    bf16_split(v.z, h.z, l.z);
    bf16_split(v.w, h.w, l.w);
    ((ushort4*)XH)[i] = h;
    ((ushort4*)XL)[i] = l;
}

// ---------------------------------------------------------------------------
// split_w: [Wproj;Wphase] fp32 (1792x1024) -> WH, WL bf16
// ---------------------------------------------------------------------------
__global__ __launch_bounds__(256) void split_w_kernel(
    const float* __restrict__ Wproj, const float* __restrict__ Wphase,
    unsigned short* __restrict__ WH, unsigned short* __restrict__ WL)
{
    int i = blockIdx.x * 256 + threadIdx.x;    // x4 floats
    int elem = i << 2;
    int row = elem >> 10;
    int col = elem & 1023;
    const float* src = (row < 1536) ? (Wproj + (size_t)row * 1024 + col)
                                    : (Wphase + (size_t)(row - 1536) * 1024 + col);
    float4 v = *(const float4*)src;
    ushort4 h, l;
    bf16_split(v.x, h.x, l.x);
    bf16_split(v.y, h.y, l.y);
    bf16_split(v.z, h.z, l.z);
    bf16_split(v.w, h.w, l.w);
    ((ushort4*)WH)[i] = h;
    ((ushort4*)WL)[i] = l;
}

// ---------------------------------------------------------------------------
// pack_wres: W_res fp32 (1024 x 1022) -> WPH bf16 (1024 x 1024), padded 0
// (single bf16 on the W_res side; rho side keeps hi+lo)
// ---------------------------------------------------------------------------
__global__ __launch_bounds__(256) void pack_wres_kernel(
    const float* __restrict__ Wres, unsigned short* __restrict__ WPH)
{
    int idx = blockIdx.x * 256 + threadIdx.x;   // 0 .. 1024*1024-1
    int d = idx >> 10;
    int j = idx & 1023;
    float v = (j < 1022) ? Wres[(size_t)d * 1022 + j] : 0.0f;
    unsigned u = __float_as_uint(v);
    unsigned r = u + 0x7FFFu + ((u >> 16) & 1u);
    WPH[idx] = (unsigned short)(r >> 16);
}

// ---------------------------------------------------------------------------
// GEMM1-full (3-term split-bf16): PT rows 256..767 (omega, phi) — these feed
// the oscillator angle (amplified by log-position <= 8.3) and need ~fp32.
//   jt = blockIdx.y + 2
// ---------------------------------------------------------------------------
__global__ __launch_bounds__(256, 3) void gemm1_full_kernel(
    const unsigned short* __restrict__ WH, const unsigned short* __restrict__ WL,
    const unsigned short* __restrict__ XH, const unsigned short* __restrict__ XL,
    const float* __restrict__ bproj, float* __restrict__ PT)
{
    __shared__ __attribute__((aligned(16))) unsigned short AH[4096];
    __shared__ __attribute__((aligned(16))) unsigned short AL[4096];
    __shared__ __attribute__((aligned(16))) unsigned short BH[4096];
    __shared__ __attribute__((aligned(16))) unsigned short BL[4096];

    const int tid  = threadIdx.x;
    const int lane = tid & 63;
    const int w    = tid >> 6;          // wave 0..3
    const int wm   = w >> 1, wn = w & 1;
    const int m0   = (blockIdx.y + 2) * 128;  // j tile (rows 256..767)
    const int n0   = blockIdx.x * 128;        // r tile
    const int fr   = lane & 15;
    const int fq   = lane >> 4;         // 0..3

    f32x4 acc[4][4];
    #pragma unroll
    for (int i = 0; i < 4; i++)
        #pragma unroll
        for (int j = 0; j < 4; j++) acc[i][j] = (f32x4){0.f, 0.f, 0.f, 0.f};

    for (int kc = 0; kc < 32; kc++) {
        const int kbase = kc * 32;
        __syncthreads();
        #pragma unroll
        for (int t = 0; t < 2; t++) {
            int G  = w * 128 + t * 64 + lane;       // granule index 0..511
            int gm = G & 127;
            int gq = G >> 7;
            size_t offA = (size_t)(m0 + gm) * 1024 + kbase + gq * 8;
            size_t offB = (size_t)(n0 + gm) * 1024 + kbase + gq * 8;
            int ldsg = (w * 128 + t * 64) * 8;      // wave-uniform base (shorts)
            GL2LDS(WH + offA, &AH[ldsg]);
            GL2LDS(WL + offA, &AL[ldsg]);
            GL2LDS(XH + offB, &BH[ldsg]);
            GL2LDS(XL + offB, &BL[ldsg]);
        }
        __syncthreads();

        s16x8 ah[4], al[4], bh[4], bl[4];
        #pragma unroll
        for (int f = 0; f < 4; f++) {
            int aoff = (fq * 128 + wm * 64 + f * 16 + fr) * 8;
            int boff = (fq * 128 + wn * 64 + f * 16 + fr) * 8;
            ah[f] = *(const s16x8*)&AH[aoff];
            al[f] = *(const s16x8*)&AL[aoff];
            bh[f] = *(const s16x8*)&BH[boff];
            bl[f] = *(const s16x8*)&BL[boff];
        }
        #pragma unroll
        for (int i = 0; i < 4; i++)
            #pragma unroll
            for (int j = 0; j < 4; j++) {
                acc[i][j] = __builtin_amdgcn_mfma_f32_16x16x32_bf16(ah[i], bh[j], acc[i][j], 0, 0, 0);
                acc[i][j] = __builtin_amdgcn_mfma_f32_16x16x32_bf16(ah[i], bl[j], acc[i][j], 0, 0, 0);
                acc[i][j] = __builtin_amdgcn_mfma_f32_16x16x32_bf16(al[i], bh[j], acc[i][j], 0, 0, 0);
            }
    }

    #pragma unroll
    for (int i = 0; i < 4; i++) {
        int mbase = m0 + wm * 64 + i * 16 + fq * 4;
        #pragma unroll
        for (int j = 0; j < 4; j++) {
            int n = n0 + wn * 64 + j * 16 + fr;
            #pragma unroll
            for (int rg = 0; rg < 4; rg++) {
                int m = mbase + rg;
                PT[(size_t)m * NROW + n] = acc[i][j][rg] + bproj[m];
            }
        }
    }
}

// ---------------------------------------------------------------------------
// GEMM1-lite (single bf16): PT rows 0..255, 768..1791 (A, alpha, g, beta, pq).
// Sigmoid-bounded outputs — bf16 precision ample. BK=64: half the barriers
// of the BK=32 version (this GEMM is the most sync/staging-bound: 1 MFMA
// per frag-pair vs 3 in the full path).
//   jt = (blockIdx.y < 2) ? blockIdx.y : blockIdx.y + 4
// ---------------------------------------------------------------------------
__global__ __launch_bounds__(256, 4) void gemm1_lite_kernel(
    const unsigned short* __restrict__ WH, const unsigned short* __restrict__ XH,
    const float* __restrict__ bproj, const float* __restrict__ bphase,
    float* __restrict__ PT)
{
    __shared__ __attribute__((aligned(16))) unsigned short AH[8192]; // 128x64
    __shared__ __attribute__((aligned(16))) unsigned short BH[8192];

    const int tid  = threadIdx.x;
    const int lane = tid & 63;
    const int w    = tid >> 6;
    const int wm   = w >> 1, wn = w & 1;
    const int yt   = blockIdx.y;
    const int jt   = (yt < 2) ? yt : yt + 4;
    const int m0   = jt * 128;
    const int n0   = blockIdx.x * 128;
    const int fr   = lane & 15;
    const int fq   = lane >> 4;

    f32x4 acc[4][4];
    #pragma unroll
    for (int i = 0; i < 4; i++)
        #pragma unroll
        for (int j = 0; j < 4; j++) acc[i][j] = (f32x4){0.f, 0.f, 0.f, 0.f};

    for (int kc = 0; kc < 16; kc++) {
        const int kbase = kc * 64;
        __syncthreads();
        #pragma unroll
        for (int t = 0; t < 4; t++) {
            int G  = t * 256 + tid;                 // granule index 0..1023
            int gm = G & 127;
            int gq = G >> 7;                        // ksub 0..7
            size_t offA = (size_t)(m0 + gm) * 1024 + kbase + gq * 8;
            size_t offB = (size_t)(n0 + gm) * 1024 + kbase + gq * 8;
            int ldsg = (t * 256 + w * 64) * 8;      // wave-uniform base (shorts)
            GL2LDS(WH + offA, &AH[ldsg]);
            GL2LDS(XH + offB, &BH[ldsg]);
        }
        __syncthreads();

        #pragma unroll
        for (int s = 0; s < 2; s++) {
            s16x8 ah[4], bh[4];
            #pragma unroll
            for (int f = 0; f < 4; f++) {
                int aoff = (((s * 4 + fq) * 128) + wm * 64 + f * 16 + fr) * 8;
                int boff = (((s * 4 + fq) * 128) + wn * 64 + f * 16 + fr) * 8;
                ah[f] = *(const s16x8*)&AH[aoff];
                bh[f] = *(const s16x8*)&BH[boff];
            }
            #pragma unroll
            for (int i = 0; i < 4; i++)
                #pragma unroll
                for (int j = 0; j < 4; j++)
                    acc[i][j] = __builtin_amdgcn_mfma_f32_16x16x32_bf16(ah[i], bh[j], acc[i][j], 0, 0, 0);
        }
    }

    #pragma unroll
    for (int i = 0; i < 4; i++) {
        int mbase = m0 + wm * 64 + i * 16 + fq * 4;
        #pragma unroll
        for (int j = 0; j < 4; j++) {
            int n = n0 + wn * 64 + j * 16 + fr;
            #pragma unroll
            for (int rg = 0; rg < 4; rg++) {
                int m = mbase + rg;
                float bias = (m < 1536) ? bproj[m] : bphase[m - 1536];
                PT[(size_t)m * NROW + n] = acc[i][j][rg] + bias;
            }
        }
    }
}

// ---------------------------------------------------------------------------
// Scan kernel: one block per (b, k) channel.
// cs/sn carried in registers between pass 1 and pass 3 (same thread owns the
// same n in both passes) — removes a sincos + softplus + log1p + 2 HBM
// re-reads per element from pass 3.
// ---------------------------------------------------------------------------
__global__ __launch_bounds__(256) void scan_kernel(float* PT,
                                                   const float* lambda_ptr)
{
    const int bx = blockIdx.x;         // 0..1023
    const int k = bx & 255;
    const int b = bx >> 8;
    const int t = threadIdx.x;         // 0..255
    const size_t colb = (size_t)b * NSEQ;
    const size_t R = NROW;

    float* rowA  = PT + (size_t)(k)        * R + colb;  // a_raw -> rho_re
    float* rowW  = PT + (size_t)(256 + k)  * R + colb;  // w_raw -> rho_im
    float* rowP  = PT + (size_t)(512 + k)  * R + colb;  // p_raw -> g
    float* rowAl = PT + (size_t)(768 + k)  * R + colb;  // al_raw
    float* rowG  = PT + (size_t)(1024 + k) * R + colb;  // g_raw
    float* rowBe = PT + (size_t)(1280 + k) * R + colb;  // be_raw
    float* rowPq = PT + (size_t)(1536 + k) * R + colb;  // phase query

    __shared__ float s_al[NSEQ + 256];
    __shared__ float s_rr[NSEQ + 256];
    __shared__ float s_ri[NSEQ + 256];
    __shared__ float s_sa[256], s_sbr[256], s_sbi[256];

    const float lam = *lambda_ptr;

    float cs_r[16], sn_r[16];          // fully unrolled -> stays in VGPRs

    #pragma unroll
    for (int i = 0; i < 16; i++) {
        int n = i * 256 + t;
        float araw = rowA[n];
        float wraw = rowW[n];
        float praw = rowP[n];
        float alraw = rowAl[n];
        float A     = 3.0f * sigm(araw);
        float alpha = sigm(alraw);
        float omega = softplusf_(wraw);
        float ang   = fmaf(omega, log1pf((float)n), praw);
        float sn, cs;
        sincosf(ang, &sn, &cs);
        cs_r[i] = cs;
        sn_r[i] = sn;
        float amp = (1.0f - alpha) * A;
        int pidx = n + (n >> 4);
        s_al[pidx] = alpha;
        s_rr[pidx] = amp * cs;
        s_ri[pidx] = amp * sn;
    }
    __syncthreads();

    {
        float ap = 1.0f, br = 0.0f, bi = 0.0f;
        int base = t * 17;
        #pragma unroll
        for (int i = 0; i < 16; i++) {
            float a = s_al[base + i];
            br = fmaf(a, br, s_rr[base + i]);
            bi = fmaf(a, bi, s_ri[base + i]);
            ap *= a;
        }
        s_sa[t] = ap; s_sbr[t] = br; s_sbi[t] = bi;
    }
    __syncthreads();

    for (int off = 1; off < 256; off <<= 1) {
        float a2 = s_sa[t], b2r = s_sbr[t], b2i = s_sbi[t];
        float a1 = 1.0f, b1r = 0.0f, b1i = 0.0f;
        if (t >= off) { a1 = s_sa[t - off]; b1r = s_sbr[t - off]; b1i = s_sbi[t - off]; }
        __syncthreads();
        s_sa[t]  = a1 * a2;
        s_sbr[t] = fmaf(a2, b1r, b2r);
        s_sbi[t] = fmaf(a2, b1i, b2i);
        __syncthreads();
    }

    {
        float cr = 0.0f, ci = 0.0f;
        if (t > 0) { cr = s_sbr[t - 1]; ci = s_sbi[t - 1]; }
        int base = t * 17;
        #pragma unroll
        for (int i = 0; i < 16; i++) {
            float a = s_al[base + i];
            cr = fmaf(a, cr, s_rr[base + i]);
            ci = fmaf(a, ci, s_ri[base + i]);
            s_rr[base + i] = cr;
            s_ri[base + i] = ci;
        }
    }
    __syncthreads();

    #pragma unroll
    for (int i = 0; i < 16; i++) {
        int n = i * 256 + t;
        float beraw = rowBe[n];
        float graw = rowG[n];
        float pq = rowPq[n];

        float cs = cs_r[i];
        float sn = sn_r[i];

        int pidx = n + (n >> 4);
        float rr = s_rr[pidx], ri = s_ri[pidx];
        float beta = sigm(beraw);
        float g = sigm(graw);

        float readout = rr * cs + ri * sn;
        rr -= beta * readout * cs;
        ri -= beta * readout * sn;

        float modulus = sqrtf(rr * rr + ri * ri + 1e-8f);
        float scale = fmaxf(modulus, 1.0f);
        rr /= scale; ri /= scale;

        float rho_re = rr * cs + ri * sn;
        float rho_im = -rr * sn + ri * cs;

        float rho_norm = sqrtf(rho_re * rho_re + rho_im * rho_im + 1e-8f);
        float sq, cq;
        sincosf(pq, &sq, &cq);
        float pa = (rho_re * cq + rho_im * sq) / rho_norm;
        float gate = sigm(lam * pa);
        rho_re *= gate;
        rho_im *= gate;

        rowA[n] = rho_re;
        rowW[n] = rho_im;
        rowP[n] = g;
    }
}

// ---------------------------------------------------------------------------
// pack_rho: fused cross-products + transpose + bf16 split.
// ---------------------------------------------------------------------------
__global__ __launch_bounds__(256) void pack_rho_kernel(
    const float* __restrict__ PT, unsigned short* __restrict__ RTH,
    unsigned short* __restrict__ RTL)
{
    __shared__ float s_re[256 * 33];
    __shared__ float s_im[256 * 33];
    __shared__ float s_g [256 * 33];

    const int tid = threadIdx.x;
    const int r0 = blockIdx.x * 32;

    {
        int lr = tid & 31;
        int k0 = tid >> 5;       // 0..7
        for (int it = 0; it < 32; it++) {
            int k = it * 8 + k0;
            size_t go = (size_t)k * NROW + r0 + lr;
            s_re[k * 33 + lr] = PT[go];
            s_im[k * 33 + lr] = PT[(size_t)256 * NROW + go];
            s_g [k * 33 + lr] = PT[(size_t)512 * NROW + go];
        }
    }
    __syncthreads();

    const int r = tid >> 3;      // 0..31
    const int c = tid & 7;       // 0..7
    for (int i = 0; i < 16; i++) {
        int jb = (c + 8 * i) * 8;       // 0..1016, step 8
        unsigned short h[8], l[8];
        #pragma unroll
        for (int e = 0; e < 8; e++) {
            int j = jb + e;
            float v;
            if (j < 256) {
                v = s_g[j * 33 + r] * s_re[j * 33 + r];
            } else if (j < 512) {
                int k = j - 256;
                v = s_g[k * 33 + r] * s_im[k * 33 + r];
            } else if (j < 767) {
                int k = j - 512;
                float gc = 0.5f * (s_g[k * 33 + r] + s_g[(k + 1) * 33 + r]);
                v = gc * (s_re[k * 33 + r] * s_re[(k + 1) * 33 + r]
                        - s_im[k * 33 + r] * s_im[(k + 1) * 33 + r]);
            } else if (j < 1022) {
                int k = j - 767;
                float gc = 0.5f * (s_g[k * 33 + r] + s_g[(k + 1) * 33 + r]);
                v = gc * (s_re[k * 33 + r] * s_im[(k + 1) * 33 + r]
                        + s_im[k * 33 + r] * s_re[(k + 1) * 33 + r]);
            } else {
                v = 0.0f;
            }
            bf16_split(v, h[e], l[e]);
        }
        size_t off = (size_t)(r0 + r) * 1024 + jb;
        s16x8 hv, lv;
        #pragma unroll
        for (int e = 0; e < 8; e++) { hv[e] = (short)h[e]; lv[e] = (short)l[e]; }
        *(s16x8*)&RTH[off] = hv;
        *(s16x8*)&RTL[off] = lv;
    }
}

// ---------------------------------------------------------------------------
// GEMM2 (2-term: W_res bf16, rho hi+lo): out[r,d] = rs * sum_j RT[r,j]*WP[d,j]
// ---------------------------------------------------------------------------
__global__ __launch_bounds__(256, 3) void gemm2_kernel(
    const unsigned short* __restrict__ WPH,
    const unsigned short* __restrict__ RTH, const unsigned short* __restrict__ RTL,
    const float* __restrict__ rs_ptr, float* __restrict__ out)
{
    __shared__ __attribute__((aligned(16))) unsigned short AH[4096];
    __shared__ __attribute__((aligned(16))) unsigned short BH[4096];
    __shared__ __attribute__((aligned(16))) unsigned short BL[4096];

    const int tid  = threadIdx.x;
    const int lane = tid & 63;
    const int w    = tid >> 6;
    const int wm   = w >> 1, wn = w & 1;
    const int m0   = blockIdx.y * 128;  // d tile
    const int n0   = blockIdx.x * 128;  // r tile
    const int fr   = lane & 15;
    const int fq   = lane >> 4;
    const float rs = *rs_ptr;

    f32x4 acc[4][4];
    #pragma unroll
    for (int i = 0; i < 4; i++)
        #pragma unroll
        for (int j = 0; j < 4; j++) acc[i][j] = (f32x4){0.f, 0.f, 0.f, 0.f};

    for (int kc = 0; kc < 32; kc++) {
        const int kbase = kc * 32;
        __syncthreads();
        #pragma unroll
        for (int t = 0; t < 2; t++) {
            int G  = w * 128 + t * 64 + lane;
            int gm = G & 127;
            int gq = G >> 7;
            size_t offA = (size_t)(m0 + gm) * 1024 + kbase + gq * 8;
            size_t offB = (size_t)(n0 + gm) * 1024 + kbase + gq * 8;
            int ldsg = (w * 128 + t * 64) * 8;
            GL2LDS(WPH + offA, &AH[ldsg]);
            GL2LDS(RTH + offB, &BH[ldsg]);
            GL2LDS(RTL + offB, &BL[ldsg]);
        }
        __syncthreads();

        s16x8 ah[4], bh[4], bl[4];
        #pragma unroll
        for (int f = 0; f < 4; f++) {
            int aoff = (fq * 128 + wm * 64 + f * 16 + fr) * 8;
            int boff = (fq * 128 + wn * 64 + f * 16 + fr) * 8;
            ah[f] = *(const s16x8*)&AH[aoff];
            bh[f] = *(const s16x8*)&BH[boff];
            bl[f] = *(const s16x8*)&BL[boff];
        }
        #pragma unroll
        for (int i = 0; i < 4; i++)
            #pragma unroll
            for (int j = 0; j < 4; j++) {
                acc[i][j] = __builtin_amdgcn_mfma_f32_16x16x32_bf16(ah[i], bh[j], acc[i][j], 0, 0, 0);
                acc[i][j] = __builtin_amdgcn_mfma_f32_16x16x32_bf16(ah[i], bl[j], acc[i][j], 0, 0, 0);
            }
    }

    #pragma unroll
    for (int i = 0; i < 4; i++) {
        int d = m0 + wm * 64 + i * 16 + fq * 4;
        #pragma unroll
        for (int j = 0; j < 4; j++) {
            int n = n0 + wn * 64 + j * 16 + fr;
            float4 v = { rs * acc[i][j][0], rs * acc[i][j][1],
                         rs * acc[i][j][2], rs * acc[i][j][3] };
            *(float4*)&out[(size_t)n * 1024 + d] = v;
        }
    }
}

// ---------------------------------------------------------------------------
extern "C" void kernel_launch(void* const* d_in, const int* in_sizes, int n_in,
                              void* d_out, int out_size, void* d_ws, size_t ws_size,
                              hipStream_t stream)
{
    const float* x      = (const float*)d_in[0];
    const float* Wproj  = (const float*)d_in[1];
    const float* bproj  = (const float*)d_in[2];
    const float* Wres   = (const float*)d_in[3];
    const float* Wphase = (const float*)d_in[4];
    const float* bphase = (const float*)d_in[5];
    const float* lam    = (const float*)d_in[6];
    const float* rs     = (const float*)d_in[7];
    float* out = (float*)d_out;

    // workspace layout (~124.8 MB):
    //   PT fp32 [1792][16384]           (117.4 MB)
    //   WH, WL bf16 [1792][1024]        (7.3 MB, after PT)
    // aliased into dead PT rows:
    //   RTH bf16 [16384][1024] = PT rows  768..1279
    //   RTL bf16 [16384][1024] = PT rows 1280..1791
    //   WPH bf16 [1024][1024]  = PT rows 0..31 (after pack_rho)
    // d_out doubles as XH/XL bf16 scratch until gemm2 overwrites it.
    float* PT = (float*)d_ws;
    unsigned short* WH  = (unsigned short*)((char*)d_ws + (size_t)JTOT * NROW * 4);
    unsigned short* WL  = WH + (size_t)JTOT * 1024;
    unsigned short* RTH = (unsigned short*)(PT + (size_t)768 * NROW);
    unsigned short* RTL = RTH + (size_t)NROW * 1024;
    unsigned short* WPH = (unsigned short*)PT;
    unsigned short* XH  = (unsigned short*)d_out;
    unsigned short* XL  = XH + (size_t)NROW * 1024;

    hipLaunchKernelGGL(split_x_kernel, dim3(NROW * D_MODEL / 1024), dim3(256), 0, stream,
                       x, XH, XL);
    hipLaunchKernelGGL(split_w_kernel, dim3(JTOT * D_MODEL / 1024), dim3(256), 0, stream,
                       Wproj, Wphase, WH, WL);
    hipLaunchKernelGGL(gemm1_full_kernel, dim3(NROW / 128, 4), dim3(256), 0, stream,
                       WH, WL, XH, XL, bproj, PT);
    hipLaunchKernelGGL(gemm1_lite_kernel, dim3(NROW / 128, 10), dim3(256), 0, stream,
                       WH, XH, bproj, bphase, PT);
    hipLaunchKernelGGL(scan_kernel, dim3(BATCH * KOSC), dim3(256), 0, stream,
                       PT, lam);
    hipLaunchKernelGGL(pack_rho_kernel, dim3(NROW / 32), dim3(256), 0, stream,
                       PT, RTH, RTL);
    hipLaunchKernelGGL(pack_wres_kernel, dim3(1024 * 1024 / 256), dim3(256), 0, stream,
                       Wres, WPH);
    hipLaunchKernelGGL(gemm2_kernel, dim3(NROW / 128, 1024 / 128), dim3(256), 0, stream,
                       WPH, RTH, RTL, rs, out);
}